// Round 2
// baseline (422.317 us; speedup 1.0000x reference)
//
#include <hip/hip_runtime.h>
#include <stdint.h>

typedef unsigned short u16;
typedef __attribute__((ext_vector_type(8))) short short8;
typedef __attribute__((ext_vector_type(4))) float f32x4;

#define MFMA16 __builtin_amdgcn_mfma_f32_16x16x32_bf16

#define GLOAD_LDS16(gsrc, ldst) \
  __builtin_amdgcn_global_load_lds((const __attribute__((address_space(1))) void*)(gsrc), \
                                   (__attribute__((address_space(3))) void*)(ldst), 16, 0, 0)

__device__ __forceinline__ u16 f2bf(float x) {
  union { float f; uint32_t u; } v; v.f = x;
  uint32_t r = v.u + 0x7FFFu + ((v.u >> 16) & 1u);
  return (u16)(r >> 16);
}
__device__ __forceinline__ float bf2f(u16 b) {
  union { uint32_t u; float f; } v; v.u = ((uint32_t)b) << 16;
  return v.f;
}

// ---------------- convert f32 -> bf16 (elementwise, vectorized) ----------------
__global__ __launch_bounds__(256) void convert_bf16_kernel(
    const float* __restrict__ in, u16* __restrict__ out, int n) {
  int i = (blockIdx.x * 256 + threadIdx.x) * 8;
  if (i >= n) return;
  float4 a = *(const float4*)(in + i);
  float4 b = *(const float4*)(in + i + 4);
  short8 t;
  t[0] = (short)f2bf(a.x); t[1] = (short)f2bf(a.y);
  t[2] = (short)f2bf(a.z); t[3] = (short)f2bf(a.w);
  t[4] = (short)f2bf(b.x); t[5] = (short)f2bf(b.y);
  t[6] = (short)f2bf(b.z); t[7] = (short)f2bf(b.w);
  *(short8*)(out + i) = t;
}

// ---------------- transpose f32 [K][N] -> bf16 [N][K] (64x64 tiles) ----------------
__global__ __launch_bounds__(256) void transpose_w64(
    const float* __restrict__ W, u16* __restrict__ WT, int KK, int NN) {
  __shared__ float tile[64][68];
  const int t = threadIdx.x;
  const int k0 = blockIdx.x * 64, n0 = blockIdx.y * 64;
  {
    int r = t >> 2, c0 = (t & 3) * 16;
    const float* src = W + (size_t)(k0 + r) * NN + n0 + c0;
#pragma unroll
    for (int j = 0; j < 16; j += 4) {
      float4 v = *(const float4*)(src + j);
      tile[r][c0 + j + 0] = v.x; tile[r][c0 + j + 1] = v.y;
      tile[r][c0 + j + 2] = v.z; tile[r][c0 + j + 3] = v.w;
    }
  }
  __syncthreads();
  {
    int n = t >> 2, kq = (t & 3) * 16;
    short8 t0, t1;
#pragma unroll
    for (int j = 0; j < 8; ++j)  t0[j] = (short)f2bf(tile[kq + j][n]);
#pragma unroll
    for (int j = 0; j < 8; ++j)  t1[j] = (short)f2bf(tile[kq + 8 + j][n]);
    u16* dst = WT + (size_t)(n0 + n) * KK + k0 + kq;
    *(short8*)dst = t0;
    *(short8*)(dst + 8) = t1;
  }
}

// ---------------- transpose V bf16 [b*2048+s][h*64+c] -> VT [(b*16+h)*64+c][s] ----------------
__global__ __launch_bounds__(256) void transpose_v64(
    const u16* __restrict__ vin, u16* __restrict__ vout) {
  __shared__ u16 tile[64][80];
  const int t = threadIdx.x;
  const int s0 = blockIdx.x * 64;
  const int bh = blockIdx.y;  // b*16+h
  const int b = bh >> 4, h = bh & 15;
  {
    int r = t >> 2, c0 = (t & 3) * 16;
    const u16* src = vin + (size_t)(b * 2048 + s0 + r) * 1024 + h * 64 + c0;
    *(short8*)&tile[r][c0] = *(const short8*)src;
    *(short8*)&tile[r][c0 + 8] = *(const short8*)(src + 8);
  }
  __syncthreads();
  {
    int c = t >> 2, s4 = (t & 3) * 16;
    short8 t0, t1;
#pragma unroll
    for (int j = 0; j < 8; ++j) t0[j] = (short)tile[s4 + j][c];
#pragma unroll
    for (int j = 0; j < 8; ++j) t1[j] = (short)tile[s4 + 8 + j][c];
    u16* dst = vout + (size_t)(bh * 64 + c) * 2048 + s0 + s4;
    *(short8*)dst = t0;
    *(short8*)(dst + 8) = t1;
  }
}

// ---------------- GEMM: D[r][n] = sum_k A[r][k]*BT[n][k], m97-style 128x128/BK=64 ----------------
// mode -1: z = blockIdx.z selects weight (0=q scale, 1=k, 2=v, 3=g sigmoid+bg), bf16 out
// mode  4: final, f32 out + bo
__global__ __launch_bounds__(256) void gemm_bt128(
    const u16* __restrict__ A, const u16* __restrict__ BTbase,
    void* __restrict__ dstbase, const float* __restrict__ bvec, int mode) {
  const int K = 1024;
  const int tid = threadIdx.x, lane = tid & 63, w = tid >> 6;
  const int wr = w >> 1, wc = w & 1;
  const int l15 = lane & 15, lg = lane >> 4;
  const int z = (mode < 0) ? (int)blockIdx.z : mode;
  const u16* BT = (mode < 0) ? BTbase + (size_t)z * 1024 * 1024 : BTbase;
  const int rbase = blockIdx.x * 128;
  const int nbase = blockIdx.y * 128;
  __shared__ u16 lsA[128 * 64];
  __shared__ u16 lsB[128 * 64];
  f32x4 acc[4][4] = {};
  const int col8 = (lane & 7) * 8;
  for (int kt = 0; kt < K / 64; ++kt) {
#pragma unroll
    for (int i = 0; i < 4; ++i) {
      int row = w * 32 + i * 8 + (lane >> 3);
      const u16* sa = A + (size_t)(rbase + row) * K + kt * 64 + col8;
      GLOAD_LDS16(sa, lsA + (w * 32 + i * 8) * 64 + lane * 8);
      const u16* sb = BT + (size_t)(nbase + row) * K + kt * 64 + col8;
      GLOAD_LDS16(sb, lsB + (w * 32 + i * 8) * 64 + lane * 8);
    }
    __syncthreads();
#pragma unroll
    for (int kk = 0; kk < 2; ++kk) {
      short8 af[4], bfr[4];
#pragma unroll
      for (int m = 0; m < 4; ++m)
        af[m] = *(const short8*)&lsA[(wr * 64 + m * 16 + l15) * 64 + kk * 32 + lg * 8];
#pragma unroll
      for (int n = 0; n < 4; ++n)
        bfr[n] = *(const short8*)&lsB[(wc * 64 + n * 16 + l15) * 64 + kk * 32 + lg * 8];
#pragma unroll
      for (int m = 0; m < 4; ++m)
#pragma unroll
        for (int n = 0; n < 4; ++n)
          acc[m][n] = MFMA16(af[m], bfr[n], acc[m][n], 0, 0, 0);
    }
    __syncthreads();
  }
  const int r0 = rbase + wr * 64;
  const int c0 = nbase + wc * 64;
  if (z == 4) {
    float* out = (float*)dstbase;
#pragma unroll
    for (int m = 0; m < 4; ++m)
#pragma unroll
      for (int n = 0; n < 4; ++n)
#pragma unroll
        for (int i = 0; i < 4; ++i) {
          int r = r0 + m * 16 + lg * 4 + i;
          int c = c0 + n * 16 + l15;
          out[(size_t)r * 1024 + c] = acc[m][n][i] + bvec[c];
        }
  } else {
    u16* dq = (u16*)dstbase + (size_t)z * 4096 * 1024;
#pragma unroll
    for (int m = 0; m < 4; ++m)
#pragma unroll
      for (int n = 0; n < 4; ++n)
#pragma unroll
        for (int i = 0; i < 4; ++i) {
          int r = r0 + m * 16 + lg * 4 + i;
          int c = c0 + n * 16 + l15;
          float v = acc[m][n][i];
          if (z == 0) v *= 0.125f;                                   // q / sqrt(64)
          else if (z == 3) v = 1.f / (1.f + __expf(-(v + bvec[c]))); // sigmoid gate
          dq[(size_t)r * 1024 + c] = f2bf(v);
        }
  }
}

// ---------------- flash attention with pair bias + mask + gate ----------------
// grid (32 q-tiles, 16 heads), 8 waves: wave w -> batch w>>2, q rows qt*64+(w&3)*16..+15.
// The 64x64 f32 bias tile is shared by all 8 waves, async-staged (global_load_lds)
// into a double-buffered, XOR-swizzled LDS layout: 16B granule (row,c4) stored at
// granule index row*16 + (c4 ^ (row&15)). Linear LDS dest + pre-swizzled global src.
__global__ __launch_bounds__(512, 4) void attn_kernel(
    const u16* __restrict__ qws, const u16* __restrict__ kws,
    const u16* __restrict__ vt, const u16* __restrict__ gws,
    const float* __restrict__ bias, const float* __restrict__ mask,
    u16* __restrict__ og) {
  const int tid = threadIdx.x;
  const int lane = tid & 63;
  const int w = tid >> 6;       // 0..7
  const int b = w >> 2;         // batch
  const int wq = w & 3;         // q sub-tile
  const int qt = blockIdx.x;
  const int h = blockIdx.y;
  const int l15 = lane & 15;
  const int lg = lane >> 4;
  const int qb = qt * 64 + wq * 16;

  __shared__ float blds[2][4096];     // 2 x 16KB bias tiles (swizzled granules)
  __shared__ u16 plds[8][16][72];     // per-wave P tile

  const float* bias_base = bias + ((size_t)h * 2048 + qt * 64) * 2048;

  // stage one 64x64 f32 bias tile (k columns k0..k0+63) into blds[buf]
  auto stage_bias = [&](int buf, int k0) {
#pragma unroll
    for (int it = 0; it < 2; ++it) {
      int g = it * 512 + w * 64 + lane;       // granule 0..1023
      int row = g >> 4;
      int c4 = (g & 15) ^ (row & 15);         // pre-swizzled source granule
      const float* src = bias_base + (size_t)row * 2048 + k0 + c4 * 4;
      GLOAD_LDS16(src, &blds[buf][(size_t)g * 4]);
    }
  };

  short8 qf[2];
#pragma unroll
  for (int hh = 0; hh < 2; ++hh)
    qf[hh] = *(const short8*)(qws + (size_t)(b * 2048 + qb + l15) * 1024 +
                              h * 64 + hh * 32 + lg * 8);

  f32x4 O[4] = {};
  float mrow[4], lrow[4];
#pragma unroll
  for (int i = 0; i < 4; ++i) { mrow[i] = -3e38f; lrow[i] = 0.f; }

  stage_bias(0, 0);
  __syncthreads();

  for (int kb = 0; kb < 32; ++kb) {
    const int k0 = kb * 64;
    const int cur = kb & 1;
    if (kb + 1 < 32) stage_bias(cur ^ 1, (kb + 1) * 64);

    // bias fragments from LDS (swizzled layout; ~2-way banks = free)
    float bv[4][4];
#pragma unroll
    for (int ks = 0; ks < 4; ++ks)
#pragma unroll
      for (int i = 0; i < 4; ++i) {
        int row = wq * 16 + lg * 4 + i;
        int g = row * 16 + ((ks * 4 + (l15 >> 2)) ^ (row & 15));
        bv[ks][i] = blds[cur][g * 4 + (l15 & 3)];
      }

    // QK^T
    f32x4 s[4];
#pragma unroll
    for (int ks = 0; ks < 4; ++ks) {
      const u16* kp = kws + (size_t)(b * 2048 + k0 + ks * 16 + l15) * 1024 + h * 64 + lg * 8;
      short8 kf0 = *(const short8*)(kp);
      short8 kf1 = *(const short8*)(kp + 32);
      f32x4 z = {0.f, 0.f, 0.f, 0.f};
      s[ks] = MFMA16(qf[0], kf0, z, 0, 0, 0);
      s[ks] = MFMA16(qf[1], kf1, s[ks], 0, 0, 0);
    }
#pragma unroll
    for (int ks = 0; ks < 4; ++ks) {
      float mk = (mask[b * 2048 + k0 + ks * 16 + l15] - 1.0f) * 1e9f;
#pragma unroll
      for (int i = 0; i < 4; ++i) s[ks][i] += bv[ks][i] + mk;
    }

    // online softmax; q-rows live on 16-lane groups
#pragma unroll
    for (int i = 0; i < 4; ++i) {
      float t = fmaxf(fmaxf(s[0][i], s[1][i]), fmaxf(s[2][i], s[3][i]));
      t = fmaxf(t, __shfl_xor(t, 1));
      t = fmaxf(t, __shfl_xor(t, 2));
      t = fmaxf(t, __shfl_xor(t, 4));
      t = fmaxf(t, __shfl_xor(t, 8));
      float nm = fmaxf(mrow[i], t);
      float sc = __expf(mrow[i] - nm);
      mrow[i] = nm;
      float rs = 0.f;
#pragma unroll
      for (int ks = 0; ks < 4; ++ks) {
        float p = __expf(s[ks][i] - nm);
        s[ks][i] = p;
        rs += p;
      }
      rs += __shfl_xor(rs, 1); rs += __shfl_xor(rs, 2);
      rs += __shfl_xor(rs, 4); rs += __shfl_xor(rs, 8);
      lrow[i] = lrow[i] * sc + rs;
#pragma unroll
      for (int cf = 0; cf < 4; ++cf) O[cf][i] *= sc;
    }

    // P -> LDS (reshape to A-fragment layout); same-wave, no barrier needed
#pragma unroll
    for (int ks = 0; ks < 4; ++ks)
#pragma unroll
      for (int i = 0; i < 4; ++i)
        plds[w][lg * 4 + i][ks * 16 + l15] = f2bf(s[ks][i]);

    // PV
#pragma unroll
    for (int ks2 = 0; ks2 < 2; ++ks2) {
      short8 pa = *(const short8*)&plds[w][l15][ks2 * 32 + lg * 8];
#pragma unroll
      for (int cf = 0; cf < 4; ++cf) {
        short8 vf = *(const short8*)(vt + (size_t)((b * 16 + h) * 64 + cf * 16 + l15) * 2048 +
                                     k0 + ks2 * 32 + lg * 8);
        O[cf] = MFMA16(pa, vf, O[cf], 0, 0, 0);
      }
    }

    // drains this iteration's stage (issued at top -> latency hidden under compute)
    // and fences buffer reuse across waves
    __syncthreads();
  }

  // epilogue: 1/l, gate, store bf16
#pragma unroll
  for (int cf = 0; cf < 4; ++cf)
#pragma unroll
    for (int i = 0; i < 4; ++i) {
      int q = qb + lg * 4 + i;
      size_t idx = (size_t)(b * 2048 + q) * 1024 + h * 64 + cf * 16 + l15;
      float val = O[cf][i] / lrow[i];
      float g = bf2f(gws[idx]);
      og[idx] = f2bf(val * g);
    }
}

extern "C" void kernel_launch(void* const* d_in, const int* in_sizes, int n_in,
                              void* d_out, int out_size, void* d_ws, size_t ws_size,
                              hipStream_t stream) {
  const float* x    = (const float*)d_in[0];
  const float* mask = (const float*)d_in[1];
  const float* bias = (const float*)d_in[2];
  const float* wq   = (const float*)d_in[3];
  const float* wk   = (const float*)d_in[4];
  const float* wv   = (const float*)d_in[5];
  const float* wg   = (const float*)d_in[6];
  const float* bg   = (const float*)d_in[7];
  const float* wo   = (const float*)d_in[8];
  const float* bo   = (const float*)d_in[9];
  float* out = (float*)d_out;

  char* ws = (char*)d_ws;
  const size_t MB = 1ull << 20;
  u16* xb   = (u16*)(ws + 0);        // 4096x1024 bf16 input          (8 MB)
  u16* wt   = (u16*)(ws + 8 * MB);   // 4x WT [1024][1024] bf16       (8 MB)
  u16* wot  = (u16*)(ws + 16 * MB);  // WOT [1024][1024] bf16         (2 MB)
  u16* proj = (u16*)(ws + 18 * MB);  // q,k,v,g each 4096x1024 bf16   (32 MB)
  u16* vtp  = (u16*)(ws + 50 * MB);  // VT [b,h,c,s] bf16             (8 MB)
  u16* og   = (u16*)(ws + 58 * MB);  // gated attention out bf16      (8 MB)
  const size_t PSZ = (size_t)4096 * 1024;

  convert_bf16_kernel<<<2048, 256, 0, stream>>>(x, xb, 4096 * 1024);

  dim3 tg(16, 16);
  transpose_w64<<<tg, 256, 0, stream>>>(wq, wt + 0 * 1048576, 1024, 1024);
  transpose_w64<<<tg, 256, 0, stream>>>(wk, wt + 1 * 1048576, 1024, 1024);
  transpose_w64<<<tg, 256, 0, stream>>>(wv, wt + 2 * 1048576, 1024, 1024);
  transpose_w64<<<tg, 256, 0, stream>>>(wg, wt + 3 * 1048576, 1024, 1024);
  transpose_w64<<<tg, 256, 0, stream>>>(wo, wot, 1024, 1024);

  gemm_bt128<<<dim3(32, 8, 4), 256, 0, stream>>>(xb, wt, (void*)proj, bg, -1);

  transpose_v64<<<dim3(32, 32), 256, 0, stream>>>(proj + 2 * PSZ, vtp);

  attn_kernel<<<dim3(32, 16), 512, 0, stream>>>(proj, proj + PSZ, vtp, proj + 3 * PSZ,
                                                bias, mask, og);

  gemm_bt128<<<dim3(32, 8, 1), 256, 0, stream>>>(og, wot, (void*)out, bo, 4);
}

// Round 3
// 270.789 us; speedup vs baseline: 1.5596x; 1.5596x over previous
//
#include <hip/hip_runtime.h>
#include <stdint.h>

typedef unsigned short u16;
typedef __attribute__((ext_vector_type(8))) short short8;
typedef __attribute__((ext_vector_type(4))) short short4v;
typedef __attribute__((ext_vector_type(4))) float f32x4;

#define MFMA16 __builtin_amdgcn_mfma_f32_16x16x32_bf16

#define GLOAD_LDS16(gsrc, ldst) \
  __builtin_amdgcn_global_load_lds((const __attribute__((address_space(1))) void*)(gsrc), \
                                   (__attribute__((address_space(3))) void*)(ldst), 16, 0, 0)

__device__ __forceinline__ u16 f2bf(float x) {
  union { float f; uint32_t u; } v; v.f = x;
  uint32_t r = v.u + 0x7FFFu + ((v.u >> 16) & 1u);
  return (u16)(r >> 16);
}
__device__ __forceinline__ float bf2f(u16 b) {
  union { uint32_t u; float f; } v; v.u = ((uint32_t)b) << 16;
  return v.f;
}

// ---------------- convert f32 -> bf16 (elementwise, vectorized) ----------------
__global__ __launch_bounds__(256) void convert_bf16_kernel(
    const float* __restrict__ in, u16* __restrict__ out, int n) {
  int i = (blockIdx.x * 256 + threadIdx.x) * 8;
  if (i >= n) return;
  float4 a = *(const float4*)(in + i);
  float4 b = *(const float4*)(in + i + 4);
  short8 t;
  t[0] = (short)f2bf(a.x); t[1] = (short)f2bf(a.y);
  t[2] = (short)f2bf(a.z); t[3] = (short)f2bf(a.w);
  t[4] = (short)f2bf(b.x); t[5] = (short)f2bf(b.y);
  t[6] = (short)f2bf(b.z); t[7] = (short)f2bf(b.w);
  *(short8*)(out + i) = t;
}

// ---------------- transpose f32 [K][N] -> bf16 [N][K] (64x64 tiles) ----------------
__global__ __launch_bounds__(256) void transpose_w64(
    const float* __restrict__ W, u16* __restrict__ WT, int KK, int NN) {
  __shared__ float tile[64][68];
  const int t = threadIdx.x;
  const int k0 = blockIdx.x * 64, n0 = blockIdx.y * 64;
  {
    int r = t >> 2, c0 = (t & 3) * 16;
    const float* src = W + (size_t)(k0 + r) * NN + n0 + c0;
#pragma unroll
    for (int j = 0; j < 16; j += 4) {
      float4 v = *(const float4*)(src + j);
      tile[r][c0 + j + 0] = v.x; tile[r][c0 + j + 1] = v.y;
      tile[r][c0 + j + 2] = v.z; tile[r][c0 + j + 3] = v.w;
    }
  }
  __syncthreads();
  {
    int n = t >> 2, kq = (t & 3) * 16;
    short8 t0, t1;
#pragma unroll
    for (int j = 0; j < 8; ++j)  t0[j] = (short)f2bf(tile[kq + j][n]);
#pragma unroll
    for (int j = 0; j < 8; ++j)  t1[j] = (short)f2bf(tile[kq + 8 + j][n]);
    u16* dst = WT + (size_t)(n0 + n) * KK + k0 + kq;
    *(short8*)dst = t0;
    *(short8*)(dst + 8) = t1;
  }
}

// ---------------- transpose V bf16 [b*2048+s][h*64+c] -> VT [(b*16+h)*64+c][s] ----------------
__global__ __launch_bounds__(256) void transpose_v64(
    const u16* __restrict__ vin, u16* __restrict__ vout) {
  __shared__ u16 tile[64][80];
  const int t = threadIdx.x;
  const int s0 = blockIdx.x * 64;
  const int bh = blockIdx.y;  // b*16+h
  const int b = bh >> 4, h = bh & 15;
  {
    int r = t >> 2, c0 = (t & 3) * 16;
    const u16* src = vin + (size_t)(b * 2048 + s0 + r) * 1024 + h * 64 + c0;
    *(short8*)&tile[r][c0] = *(const short8*)src;
    *(short8*)&tile[r][c0 + 8] = *(const short8*)(src + 8);
  }
  __syncthreads();
  {
    int c = t >> 2, s4 = (t & 3) * 16;
    short8 t0, t1;
#pragma unroll
    for (int j = 0; j < 8; ++j) t0[j] = (short)tile[s4 + j][c];
#pragma unroll
    for (int j = 0; j < 8; ++j) t1[j] = (short)tile[s4 + 8 + j][c];
    u16* dst = vout + (size_t)(bh * 64 + c) * 2048 + s0 + s4;
    *(short8*)dst = t0;
    *(short8*)(dst + 8) = t1;
  }
}

// ---------------- GEMM: D[r][n] = sum_k A[r][k]*BT[n][k], m97-style 128x128/BK=64 ----------------
__global__ __launch_bounds__(256) void gemm_bt128(
    const u16* __restrict__ A, const u16* __restrict__ BTbase,
    void* __restrict__ dstbase, const float* __restrict__ bvec, int mode) {
  const int K = 1024;
  const int tid = threadIdx.x, lane = tid & 63, w = tid >> 6;
  const int wr = w >> 1, wc = w & 1;
  const int l15 = lane & 15, lg = lane >> 4;
  const int z = (mode < 0) ? (int)blockIdx.z : mode;
  const u16* BT = (mode < 0) ? BTbase + (size_t)z * 1024 * 1024 : BTbase;
  const int rbase = blockIdx.x * 128;
  const int nbase = blockIdx.y * 128;
  __shared__ u16 lsA[128 * 64];
  __shared__ u16 lsB[128 * 64];
  f32x4 acc[4][4] = {};
  const int col8 = (lane & 7) * 8;
  for (int kt = 0; kt < K / 64; ++kt) {
#pragma unroll
    for (int i = 0; i < 4; ++i) {
      int row = w * 32 + i * 8 + (lane >> 3);
      const u16* sa = A + (size_t)(rbase + row) * K + kt * 64 + col8;
      GLOAD_LDS16(sa, lsA + (w * 32 + i * 8) * 64 + lane * 8);
      const u16* sb = BT + (size_t)(nbase + row) * K + kt * 64 + col8;
      GLOAD_LDS16(sb, lsB + (w * 32 + i * 8) * 64 + lane * 8);
    }
    __syncthreads();
#pragma unroll
    for (int kk = 0; kk < 2; ++kk) {
      short8 af[4], bfr[4];
#pragma unroll
      for (int m = 0; m < 4; ++m)
        af[m] = *(const short8*)&lsA[(wr * 64 + m * 16 + l15) * 64 + kk * 32 + lg * 8];
#pragma unroll
      for (int n = 0; n < 4; ++n)
        bfr[n] = *(const short8*)&lsB[(wc * 64 + n * 16 + l15) * 64 + kk * 32 + lg * 8];
#pragma unroll
      for (int m = 0; m < 4; ++m)
#pragma unroll
        for (int n = 0; n < 4; ++n)
          acc[m][n] = MFMA16(af[m], bfr[n], acc[m][n], 0, 0, 0);
    }
    __syncthreads();
  }
  const int r0 = rbase + wr * 64;
  const int c0 = nbase + wc * 64;
  if (z == 4) {
    float* out = (float*)dstbase;
#pragma unroll
    for (int m = 0; m < 4; ++m)
#pragma unroll
      for (int n = 0; n < 4; ++n)
#pragma unroll
        for (int i = 0; i < 4; ++i) {
          int r = r0 + m * 16 + lg * 4 + i;
          int c = c0 + n * 16 + l15;
          out[(size_t)r * 1024 + c] = acc[m][n][i] + bvec[c];
        }
  } else {
    u16* dq = (u16*)dstbase + (size_t)z * 4096 * 1024;
#pragma unroll
    for (int m = 0; m < 4; ++m)
#pragma unroll
      for (int n = 0; n < 4; ++n)
#pragma unroll
        for (int i = 0; i < 4; ++i) {
          int r = r0 + m * 16 + lg * 4 + i;
          int c = c0 + n * 16 + l15;
          float v = acc[m][n][i];
          if (z == 0) v *= 0.125f;                                   // q / sqrt(64)
          else if (z == 3) v = 1.f / (1.f + __expf(-(v + bvec[c]))); // sigmoid gate
          dq[(size_t)r * 1024 + c] = f2bf(v);
        }
  }
}

// ---------------- flash attention, LDS-staged K/V/bias, swapped MFMA layout ----------------
// Block: 512 thr = 8 waves; wave w: kh=w>>2 (k-half), wq=w&3 (16 q-rows).
// Per iter kb: k-window [kb*64,+64); wave handles 32 k of its half.
// Swapped QK^T: S[k][q] (q lane-local) -> in-lane softmax, 4 shuffles/body.
// Swapped PV: O[c][q] accumulates with q lane-local -> scalar rescale.
// K,V,bias staged via global_load_lds with XOR-swizzled granules (both-sides swizzle).
__global__ __launch_bounds__(512, 4) void attn_kernel(
    const u16* __restrict__ qws, const u16* __restrict__ kws,
    const u16* __restrict__ vt, const u16* __restrict__ gws,
    const float* __restrict__ bias, const float* __restrict__ mask,
    u16* __restrict__ og) {
  const int tid = threadIdx.x;
  const int lane = tid & 63;
  const int w = tid >> 6;
  const int kh = w >> 2;
  const int wq = w & 3;
  const int l15 = lane & 15;
  const int lg = lane >> 4;
  // blockIdx.x packs (qt,b) so that partner blocks (same qt,h, b=0/1) are 8 apart
  // (same XCD under round-robin dispatch -> bias tile L2 reuse).
  const int bx = blockIdx.x;
  const int qt = (bx & 7) | ((bx >> 4) << 3);
  const int b = (bx >> 3) & 1;
  const int h = blockIdx.y;

  __shared__ __align__(16) u16 lsK[2][4096];    // [buf][row k(64)][granule 8 x 8 u16] swz
  __shared__ __align__(16) u16 lsV[2][4096];    // [buf][row c(64)][granule 8] swz (VT)
  __shared__ __align__(16) float lsB[2][4096];  // [buf][row q(64)][granule 16 x 4 f32] swz
  __shared__ __align__(16) u16 lsP[8][640];     // per-wave P [16 q][stride 40]

  const float* bias_base = bias + ((size_t)h * 2048 + qt * 64) * 2048;
  const u16* vt_base = vt + (size_t)((b * 16 + h) * 64) * 2048;
  const u16* k_base = kws + (size_t)(b * 2048) * 1024 + h * 64;

  // stage K,V,bias tiles for k-window kb2 into buf (4 GLOAD16 per thread)
  auto stage = [&](int buf, int kb2) {
    const int k0 = kb2 * 64;
    {  // K granule tid: row=k, 8 u16 per granule, swizzle cg^(row&7)
      int row = tid >> 3, cg = tid & 7;
      const u16* src = k_base + (size_t)(k0 + row) * 1024 + ((cg ^ (row & 7)) * 8);
      GLOAD_LDS16(src, (char*)lsK[buf] + tid * 16);
    }
    {  // V granule tid: row=c, swizzle kg^(c&7)
      int c = tid >> 3, kg = tid & 7;
      const u16* src = vt_base + (size_t)c * 2048 + k0 + ((kg ^ (c & 7)) * 8);
      GLOAD_LDS16(src, (char*)lsV[buf] + tid * 16);
    }
#pragma unroll
    for (int it = 0; it < 2; ++it) {  // bias granules tid, tid+512 (4 f32 each), swz kg4^(row&15)
      int g = it * 512 + tid;
      int row = g >> 4, kg4 = g & 15;
      const float* src = bias_base + (size_t)row * 2048 + k0 + ((kg4 ^ (row & 15)) * 4);
      GLOAD_LDS16(src, (char*)lsB[buf] + g * 16);
    }
  };

  // Q B-fragment, hoisted: lane holds Q[q=l15][c=ch*32+lg*8 ..+7]
  short8 qf[2];
#pragma unroll
  for (int ch = 0; ch < 2; ++ch)
    qf[ch] = *(const short8*)(qws + (size_t)(b * 2048 + qt * 64 + wq * 16 + l15) * 1024 +
                              h * 64 + ch * 32 + lg * 8);

  f32x4 O[4] = {};           // O[c=cf*16+lg*4+i][q=l15]
  float mreg = -3e38f, lreg = 0.f;

  stage(0, 0);
  __syncthreads();

  for (int kb = 0; kb < 32; ++kb) {
    const int cur = kb & 1;
    if (kb + 1 < 32) stage(cur ^ 1, kb + 1);

    // ---- QK^T (swapped): s[ks] = S[k=kh*32+ks*16+lg*4+i][q=l15]
    f32x4 s[2];
#pragma unroll
    for (int ks = 0; ks < 2; ++ks) {
      const int krow = kh * 32 + ks * 16 + l15;
      short8 kf0 = *(const short8*)&lsK[cur][(krow * 8 + (lg ^ (krow & 7))) * 8];
      short8 kf1 = *(const short8*)&lsK[cur][(krow * 8 + ((4 + lg) ^ (krow & 7))) * 8];
      f32x4 z = {0.f, 0.f, 0.f, 0.f};
      s[ks] = MFMA16(kf0, qf[0], z, 0, 0, 0);
      s[ks] = MFMA16(kf1, qf[1], s[ks], 0, 0, 0);
    }

    // ---- bias (staged, b128) + mask (small, L1-hot)
#pragma unroll
    for (int ks = 0; ks < 2; ++ks) {
      f32x4 bv = *(const f32x4*)&lsB[cur][(wq * 16 + l15) * 64 +
                                          (((kh * 8 + ks * 4 + lg) ^ l15) * 4)];
      f32x4 mk = *(const f32x4*)(mask + b * 2048 + kb * 64 + kh * 32 + ks * 16 + lg * 4);
#pragma unroll
      for (int i = 0; i < 4; ++i)
        s[ks][i] += bv[i] + (mk[i] - 1.0f) * 1e9f;
    }

    // ---- online softmax (q=l15 lane-local; 8 scores/lane; cross-lg via 2+2 shuffles)
    float mt = s[0][0];
#pragma unroll
    for (int ks = 0; ks < 2; ++ks)
#pragma unroll
      for (int i = 0; i < 4; ++i) mt = fmaxf(mt, s[ks][i]);
    mt = fmaxf(mt, __shfl_xor(mt, 16));
    mt = fmaxf(mt, __shfl_xor(mt, 32));
    float nm = fmaxf(mreg, mt);
    float sc = __expf(mreg - nm);
    mreg = nm;
    float rs = 0.f;
    float p[2][4];
#pragma unroll
    for (int ks = 0; ks < 2; ++ks)
#pragma unroll
      for (int i = 0; i < 4; ++i) {
        p[ks][i] = __expf(s[ks][i] - nm);
        rs += p[ks][i];
      }
    rs += __shfl_xor(rs, 16);
    rs += __shfl_xor(rs, 32);
    lreg = lreg * sc + rs;
#pragma unroll
    for (int cf = 0; cf < 4; ++cf)
#pragma unroll
      for (int i = 0; i < 4; ++i) O[cf][i] *= sc;

    // ---- P -> per-wave LDS [q=l15][k], then read B-frag (same wave, in-order DS)
#pragma unroll
    for (int ks = 0; ks < 2; ++ks) {
      short4v pk;
#pragma unroll
      for (int i = 0; i < 4; ++i) pk[i] = (short)f2bf(p[ks][i]);
      *(short4v*)&lsP[w][l15 * 40 + ks * 16 + lg * 4] = pk;
    }
    short8 pf = *(const short8*)&lsP[w][l15 * 40 + lg * 8];

    // ---- PV (swapped): O[c][q] += VT[c][k] . P[q][k]
#pragma unroll
    for (int cf = 0; cf < 4; ++cf) {
      const int crow = cf * 16 + l15;
      short8 vf = *(const short8*)&lsV[cur][(crow * 8 + ((kh * 4 + lg) ^ (crow & 7))) * 8];
      O[cf] = MFMA16(vf, pf, O[cf], 0, 0, 0);
    }

    __syncthreads();  // drains stage DMA + fences buffer swap
  }

  // ---- epilogue: combine k-halves (waves w and w+4), gate, store
  float* ob = (float*)&lsB[0][0];  // [wq][c(64)][q(16)] f32 (4096)
  float* ml = ob + 4096;           // [wq][2][16]
  if (kh == 1) {
    if (lg == 0) { ml[wq * 32 + l15] = mreg; ml[wq * 32 + 16 + l15] = lreg; }
#pragma unroll
    for (int cf = 0; cf < 4; ++cf)
#pragma unroll
      for (int i = 0; i < 4; ++i)
        ob[wq * 1024 + (cf * 16 + lg * 4 + i) * 16 + l15] = O[cf][i];
  }
  __syncthreads();
  if (kh == 0) {
    float m1 = ml[wq * 32 + l15], l1 = ml[wq * 32 + 16 + l15];
    float nm = fmaxf(mreg, m1);
    float a0 = __expf(mreg - nm), a1 = __expf(m1 - nm);
    float inv = 1.f / (lreg * a0 + l1 * a1);
#pragma unroll
    for (int cf = 0; cf < 4; ++cf)
#pragma unroll
      for (int i = 0; i < 4; ++i) {
        int idx = wq * 1024 + (cf * 16 + lg * 4 + i) * 16 + l15;
        ob[idx] = (O[cf][i] * a0 + ob[idx] * a1) * inv;
      }
  }
  __syncthreads();
  {  // cooperative gated store: thread -> (q=tid>>3, c=(tid&7)*8 ..+7), coalesced
    int q = tid >> 3, cb = (tid & 7) * 8;
    int wq2 = q >> 4, ql = q & 15;
    size_t row = (size_t)(b * 2048 + qt * 64 + q) * 1024 + h * 64 + cb;
    short8 g8 = *(const short8*)(gws + row);
    short8 o8;
#pragma unroll
    for (int j = 0; j < 8; ++j) {
      float v = ob[wq2 * 1024 + (cb + j) * 16 + ql];
      o8[j] = (short)f2bf(v * bf2f((u16)g8[j]));
    }
    *(short8*)(og + row) = o8;
  }
}

extern "C" void kernel_launch(void* const* d_in, const int* in_sizes, int n_in,
                              void* d_out, int out_size, void* d_ws, size_t ws_size,
                              hipStream_t stream) {
  const float* x    = (const float*)d_in[0];
  const float* mask = (const float*)d_in[1];
  const float* bias = (const float*)d_in[2];
  const float* wq   = (const float*)d_in[3];
  const float* wk   = (const float*)d_in[4];
  const float* wv   = (const float*)d_in[5];
  const float* wg   = (const float*)d_in[6];
  const float* bg   = (const float*)d_in[7];
  const float* wo   = (const float*)d_in[8];
  const float* bo   = (const float*)d_in[9];
  float* out = (float*)d_out;

  char* ws = (char*)d_ws;
  const size_t MB = 1ull << 20;
  u16* xb   = (u16*)(ws + 0);        // 4096x1024 bf16 input          (8 MB)
  u16* wt   = (u16*)(ws + 8 * MB);   // 4x WT [1024][1024] bf16       (8 MB)
  u16* wot  = (u16*)(ws + 16 * MB);  // WOT [1024][1024] bf16         (2 MB)
  u16* proj = (u16*)(ws + 18 * MB);  // q,k,v,g each 4096x1024 bf16   (32 MB)
  u16* vtp  = (u16*)(ws + 50 * MB);  // VT [b,h,c,s] bf16             (8 MB)
  u16* og   = (u16*)(ws + 58 * MB);  // gated attention out bf16      (8 MB)
  const size_t PSZ = (size_t)4096 * 1024;

  convert_bf16_kernel<<<2048, 256, 0, stream>>>(x, xb, 4096 * 1024);

  dim3 tg(16, 16);
  transpose_w64<<<tg, 256, 0, stream>>>(wq, wt + 0 * 1048576, 1024, 1024);
  transpose_w64<<<tg, 256, 0, stream>>>(wk, wt + 1 * 1048576, 1024, 1024);
  transpose_w64<<<tg, 256, 0, stream>>>(wv, wt + 2 * 1048576, 1024, 1024);
  transpose_w64<<<tg, 256, 0, stream>>>(wg, wt + 3 * 1048576, 1024, 1024);
  transpose_w64<<<tg, 256, 0, stream>>>(wo, wot, 1024, 1024);

  gemm_bt128<<<dim3(32, 8, 4), 256, 0, stream>>>(xb, wt, (void*)proj, bg, -1);

  transpose_v64<<<dim3(32, 32), 256, 0, stream>>>(proj + 2 * PSZ, vtp);

  attn_kernel<<<dim3(64, 16), 512, 0, stream>>>(proj, proj + PSZ, vtp, proj + 3 * PSZ,
                                                bias, mask, og);

  gemm_bt128<<<dim3(32, 8, 1), 256, 0, stream>>>(og, wot, (void*)out, bo, 4);
}

// Round 4
// 238.476 us; speedup vs baseline: 1.7709x; 1.1355x over previous
//
#include <hip/hip_runtime.h>
#include <stdint.h>

typedef unsigned short u16;
typedef __attribute__((ext_vector_type(8))) short short8;
typedef __attribute__((ext_vector_type(4))) short short4v;
typedef __attribute__((ext_vector_type(4))) float f32x4;

#define MFMA16 __builtin_amdgcn_mfma_f32_16x16x32_bf16

#define GLOAD_LDS16(gsrc, ldst) \
  __builtin_amdgcn_global_load_lds((const __attribute__((address_space(1))) void*)(gsrc), \
                                   (__attribute__((address_space(3))) void*)(ldst), 16, 0, 0)

__device__ __forceinline__ u16 f2bf(float x) {
  union { float f; uint32_t u; } v; v.f = x;
  uint32_t r = v.u + 0x7FFFu + ((v.u >> 16) & 1u);
  return (u16)(r >> 16);
}
__device__ __forceinline__ float bf2f(u16 b) {
  union { uint32_t u; float f; } v; v.u = ((uint32_t)b) << 16;
  return v.f;
}

// ---------------- convert f32 -> bf16 (elementwise, vectorized) ----------------
__global__ __launch_bounds__(256) void convert_bf16_kernel(
    const float* __restrict__ in, u16* __restrict__ out, int n) {
  int i = (blockIdx.x * 256 + threadIdx.x) * 8;
  if (i >= n) return;
  float4 a = *(const float4*)(in + i);
  float4 b = *(const float4*)(in + i + 4);
  short8 t;
  t[0] = (short)f2bf(a.x); t[1] = (short)f2bf(a.y);
  t[2] = (short)f2bf(a.z); t[3] = (short)f2bf(a.w);
  t[4] = (short)f2bf(b.x); t[5] = (short)f2bf(b.y);
  t[6] = (short)f2bf(b.z); t[7] = (short)f2bf(b.w);
  *(short8*)(out + i) = t;
}

// ---------------- transpose f32 [K][N] -> bf16 [N][K] (64x64 tiles) ----------------
__global__ __launch_bounds__(256) void transpose_w64(
    const float* __restrict__ W, u16* __restrict__ WT, int KK, int NN) {
  __shared__ float tile[64][68];
  const int t = threadIdx.x;
  const int k0 = blockIdx.x * 64, n0 = blockIdx.y * 64;
  {
    int r = t >> 2, c0 = (t & 3) * 16;
    const float* src = W + (size_t)(k0 + r) * NN + n0 + c0;
#pragma unroll
    for (int j = 0; j < 16; j += 4) {
      float4 v = *(const float4*)(src + j);
      tile[r][c0 + j + 0] = v.x; tile[r][c0 + j + 1] = v.y;
      tile[r][c0 + j + 2] = v.z; tile[r][c0 + j + 3] = v.w;
    }
  }
  __syncthreads();
  {
    int n = t >> 2, kq = (t & 3) * 16;
    short8 t0, t1;
#pragma unroll
    for (int j = 0; j < 8; ++j)  t0[j] = (short)f2bf(tile[kq + j][n]);
#pragma unroll
    for (int j = 0; j < 8; ++j)  t1[j] = (short)f2bf(tile[kq + 8 + j][n]);
    u16* dst = WT + (size_t)(n0 + n) * KK + k0 + kq;
    *(short8*)dst = t0;
    *(short8*)(dst + 8) = t1;
  }
}

// ---------------- transpose V bf16 [b*2048+s][h*64+c] -> VT [(b*16+h)*64+c][s] ----------------
__global__ __launch_bounds__(256) void transpose_v64(
    const u16* __restrict__ vin, u16* __restrict__ vout) {
  __shared__ u16 tile[64][80];
  const int t = threadIdx.x;
  const int s0 = blockIdx.x * 64;
  const int bh = blockIdx.y;  // b*16+h
  const int b = bh >> 4, h = bh & 15;
  {
    int r = t >> 2, c0 = (t & 3) * 16;
    const u16* src = vin + (size_t)(b * 2048 + s0 + r) * 1024 + h * 64 + c0;
    *(short8*)&tile[r][c0] = *(const short8*)src;
    *(short8*)&tile[r][c0 + 8] = *(const short8*)(src + 8);
  }
  __syncthreads();
  {
    int c = t >> 2, s4 = (t & 3) * 16;
    short8 t0, t1;
#pragma unroll
    for (int j = 0; j < 8; ++j) t0[j] = (short)tile[s4 + j][c];
#pragma unroll
    for (int j = 0; j < 8; ++j) t1[j] = (short)tile[s4 + 8 + j][c];
    u16* dst = vout + (size_t)(bh * 64 + c) * 2048 + s0 + s4;
    *(short8*)dst = t0;
    *(short8*)(dst + 8) = t1;
  }
}

// ---------------- GEMM: D[r][n] = sum_k A[r][k]*BT[n][k], m97-style 128x128/BK=64 ----------------
__global__ __launch_bounds__(256) void gemm_bt128(
    const u16* __restrict__ A, const u16* __restrict__ BTbase,
    void* __restrict__ dstbase, const float* __restrict__ bvec, int mode) {
  const int K = 1024;
  const int tid = threadIdx.x, lane = tid & 63, w = tid >> 6;
  const int wr = w >> 1, wc = w & 1;
  const int l15 = lane & 15, lg = lane >> 4;
  const int z = (mode < 0) ? (int)blockIdx.z : mode;
  const u16* BT = (mode < 0) ? BTbase + (size_t)z * 1024 * 1024 : BTbase;
  const int rbase = blockIdx.x * 128;
  const int nbase = blockIdx.y * 128;
  __shared__ u16 lsA[128 * 64];
  __shared__ u16 lsB[128 * 64];
  f32x4 acc[4][4] = {};
  const int col8 = (lane & 7) * 8;
  for (int kt = 0; kt < K / 64; ++kt) {
#pragma unroll
    for (int i = 0; i < 4; ++i) {
      int row = w * 32 + i * 8 + (lane >> 3);
      const u16* sa = A + (size_t)(rbase + row) * K + kt * 64 + col8;
      GLOAD_LDS16(sa, lsA + (w * 32 + i * 8) * 64 + lane * 8);
      const u16* sb = BT + (size_t)(nbase + row) * K + kt * 64 + col8;
      GLOAD_LDS16(sb, lsB + (w * 32 + i * 8) * 64 + lane * 8);
    }
    __syncthreads();
#pragma unroll
    for (int kk = 0; kk < 2; ++kk) {
      short8 af[4], bfr[4];
#pragma unroll
      for (int m = 0; m < 4; ++m)
        af[m] = *(const short8*)&lsA[(wr * 64 + m * 16 + l15) * 64 + kk * 32 + lg * 8];
#pragma unroll
      for (int n = 0; n < 4; ++n)
        bfr[n] = *(const short8*)&lsB[(wc * 64 + n * 16 + l15) * 64 + kk * 32 + lg * 8];
#pragma unroll
      for (int m = 0; m < 4; ++m)
#pragma unroll
        for (int n = 0; n < 4; ++n)
          acc[m][n] = MFMA16(af[m], bfr[n], acc[m][n], 0, 0, 0);
    }
    __syncthreads();
  }
  const int r0 = rbase + wr * 64;
  const int c0 = nbase + wc * 64;
  if (z == 4) {
    float* out = (float*)dstbase;
#pragma unroll
    for (int m = 0; m < 4; ++m)
#pragma unroll
      for (int n = 0; n < 4; ++n)
#pragma unroll
        for (int i = 0; i < 4; ++i) {
          int r = r0 + m * 16 + lg * 4 + i;
          int c = c0 + n * 16 + l15;
          out[(size_t)r * 1024 + c] = acc[m][n][i] + bvec[c];
        }
  } else {
    u16* dq = (u16*)dstbase + (size_t)z * 4096 * 1024;
#pragma unroll
    for (int m = 0; m < 4; ++m)
#pragma unroll
      for (int n = 0; n < 4; ++n)
#pragma unroll
        for (int i = 0; i < 4; ++i) {
          int r = r0 + m * 16 + lg * 4 + i;
          int c = c0 + n * 16 + l15;
          float v = acc[m][n][i];
          if (z == 0) v *= 0.125f;                                   // q / sqrt(64)
          else if (z == 3) v = 1.f / (1.f + __expf(-(v + bvec[c]))); // sigmoid gate
          dq[(size_t)r * 1024 + c] = f2bf(v);
        }
  }
}

// ---------------- flash attention, LDS-staged K/V/bias, counted-vmcnt pipeline ----------------
// Block: 512 thr = 8 waves; wave w: kh=w>>2 (k-half), wq=w&3 (16 q-rows).
// Loop body has NO global VMEM except the 4 global_load_lds of stage() -> counted
// s_waitcnt vmcnt(4) keeps next-tile DMA in flight across raw s_barrier (T3/T4).
// Mask is pre-staged to LDS as additive bf16 so it doesn't perturb vmcnt counting.
__global__ __launch_bounds__(512, 4) void attn_kernel(
    const u16* __restrict__ qws, const u16* __restrict__ kws,
    const u16* __restrict__ vt, const u16* __restrict__ gws,
    const float* __restrict__ bias, const float* __restrict__ mask,
    u16* __restrict__ og) {
  const int tid = threadIdx.x;
  const int lane = tid & 63;
  const int w = tid >> 6;
  const int kh = w >> 2;
  const int wq = w & 3;
  const int l15 = lane & 15;
  const int lg = lane >> 4;
  // blockIdx.x packs (qt,b): partner blocks (b=0/1, same qt,h) are 8 apart -> same XCD
  const int bx = blockIdx.x;
  const int qt = (bx & 7) | ((bx >> 4) << 3);
  const int b = (bx >> 3) & 1;
  const int h = blockIdx.y;

  __shared__ __align__(16) u16 lsK[2][4096];    // [buf][k(64)][8 granules x 8 u16] swz
  __shared__ __align__(16) u16 lsV[2][4096];    // [buf][c(64)][8 granules] swz (VT)
  __shared__ __align__(16) float lsB[2][4096];  // [buf][q(64)][16 granules x 4 f32] swz
  __shared__ __align__(16) u16 lsP[8][640];     // per-wave P [16 q][stride 40]
  __shared__ __align__(16) u16 lsM[2048];       // additive mask, bf16

  const float* bias_base = bias + ((size_t)h * 2048 + qt * 64) * 2048;
  const u16* vt_base = vt + (size_t)((b * 16 + h) * 64) * 2048;
  const u16* k_base = kws + (size_t)(b * 2048) * 1024 + h * 64;

  auto stage = [&](int buf, int kb2) {
    const int k0 = kb2 * 64;
    {  // K granule: row=k, swizzle cg^(row&7)
      int row = tid >> 3, cg = tid & 7;
      const u16* src = k_base + (size_t)(k0 + row) * 1024 + ((cg ^ (row & 7)) * 8);
      GLOAD_LDS16(src, (char*)lsK[buf] + tid * 16);
    }
    {  // V granule: row=c, swizzle kg^(c&7)
      int c = tid >> 3, kg = tid & 7;
      const u16* src = vt_base + (size_t)c * 2048 + k0 + ((kg ^ (c & 7)) * 8);
      GLOAD_LDS16(src, (char*)lsV[buf] + tid * 16);
    }
#pragma unroll
    for (int it = 0; it < 2; ++it) {  // bias granules (4 f32), swz kg4^(row&15)
      int g = it * 512 + tid;
      int row = g >> 4, kg4 = g & 15;
      const float* src = bias_base + (size_t)row * 2048 + k0 + ((kg4 ^ (row & 15)) * 4);
      GLOAD_LDS16(src, (char*)lsB[buf] + g * 16);
    }
  };

  // mask -> LDS as additive bf16 (one-time; keeps loop body free of global VMEM)
  {
    float4 mv = *(const float4*)(mask + b * 2048 + tid * 4);
    short4v mm;
    mm[0] = (short)f2bf((mv.x - 1.0f) * 1e9f);
    mm[1] = (short)f2bf((mv.y - 1.0f) * 1e9f);
    mm[2] = (short)f2bf((mv.z - 1.0f) * 1e9f);
    mm[3] = (short)f2bf((mv.w - 1.0f) * 1e9f);
    *(short4v*)&lsM[tid * 4] = mm;
  }

  // Q B-fragment, hoisted: lane holds Q[q=l15][c=ch*32+lg*8 ..+7]
  short8 qf[2];
#pragma unroll
  for (int ch = 0; ch < 2; ++ch)
    qf[ch] = *(const short8*)(qws + (size_t)(b * 2048 + qt * 64 + wq * 16 + l15) * 1024 +
                              h * 64 + ch * 32 + lg * 8);

  f32x4 O[4] = {};           // O[c=cf*16+lg*4+i][q=l15]
  float mreg = -3e38f, lreg = 0.f;

  stage(0, 0);
  __syncthreads();  // one-time full drain (stage(0) + mask ds_writes)

  for (int kb = 0; kb < 32; ++kb) {
    const int cur = kb & 1;
    if (kb + 1 < 32) {
      stage(cur ^ 1, kb + 1);
      asm volatile("s_waitcnt vmcnt(4)" ::: "memory");  // cur ready; next 4 stay in flight
    } else {
      asm volatile("s_waitcnt vmcnt(0)" ::: "memory");
    }
    __builtin_amdgcn_sched_barrier(0);
    __builtin_amdgcn_s_barrier();   // all waves' cur-loads landed

    // ---- QK^T (swapped): s[ks] = S[k=kh*32+ks*16+lg*4+i][q=l15]
    f32x4 s[2];
#pragma unroll
    for (int ks = 0; ks < 2; ++ks) {
      const int krow = kh * 32 + ks * 16 + l15;
      short8 kf0 = *(const short8*)&lsK[cur][(krow * 8 + (lg ^ (krow & 7))) * 8];
      short8 kf1 = *(const short8*)&lsK[cur][(krow * 8 + ((4 + lg) ^ (krow & 7))) * 8];
      f32x4 z = {0.f, 0.f, 0.f, 0.f};
      s[ks] = MFMA16(kf0, qf[0], z, 0, 0, 0);
      s[ks] = MFMA16(kf1, qf[1], s[ks], 0, 0, 0);
    }

    // ---- bias (staged f32) + mask (staged additive bf16)
#pragma unroll
    for (int ks = 0; ks < 2; ++ks) {
      f32x4 bv = *(const f32x4*)&lsB[cur][(wq * 16 + l15) * 64 +
                                          (((kh * 8 + ks * 4 + lg) ^ l15) * 4)];
      short4v mk = *(const short4v*)&lsM[kb * 64 + kh * 32 + ks * 16 + lg * 4];
#pragma unroll
      for (int i = 0; i < 4; ++i)
        s[ks][i] += bv[i] + bf2f((u16)mk[i]);
    }

    // ---- online softmax (q=l15 lane-local; cross-lg via 2+2 shuffles)
    float mt = s[0][0];
#pragma unroll
    for (int ks = 0; ks < 2; ++ks)
#pragma unroll
      for (int i = 0; i < 4; ++i) mt = fmaxf(mt, s[ks][i]);
    mt = fmaxf(mt, __shfl_xor(mt, 16));
    mt = fmaxf(mt, __shfl_xor(mt, 32));
    float nm = fmaxf(mreg, mt);
    float sc = __expf(mreg - nm);
    mreg = nm;
    float rs = 0.f;
    float p[2][4];
#pragma unroll
    for (int ks = 0; ks < 2; ++ks)
#pragma unroll
      for (int i = 0; i < 4; ++i) {
        p[ks][i] = __expf(s[ks][i] - nm);
        rs += p[ks][i];
      }
    rs += __shfl_xor(rs, 16);
    rs += __shfl_xor(rs, 32);
    lreg = lreg * sc + rs;
#pragma unroll
    for (int cf = 0; cf < 4; ++cf)
#pragma unroll
      for (int i = 0; i < 4; ++i) O[cf][i] *= sc;

    // ---- P -> per-wave LDS [q=l15][k], then read B-frag (same wave, in-order DS)
#pragma unroll
    for (int ks = 0; ks < 2; ++ks) {
      short4v pk;
#pragma unroll
      for (int i = 0; i < 4; ++i) pk[i] = (short)f2bf(p[ks][i]);
      *(short4v*)&lsP[w][l15 * 40 + ks * 16 + lg * 4] = pk;
    }
    short8 pf = *(const short8*)&lsP[w][l15 * 40 + lg * 8];

    // ---- PV (swapped): O[c][q] += VT[c][k] . P[q][k]
#pragma unroll
    for (int cf = 0; cf < 4; ++cf) {
      const int crow = cf * 16 + l15;
      short8 vf = *(const short8*)&lsV[cur][(crow * 8 + ((kh * 4 + lg) ^ (crow & 7))) * 8];
      O[cf] = MFMA16(vf, pf, O[cf], 0, 0, 0);
    }

    asm volatile("" ::: "memory");
    __builtin_amdgcn_s_barrier();   // readers of cur done before next overwrite
  }

  // ---- epilogue: combine k-halves (waves w and w+4), gate, store
  float* ob = (float*)&lsB[0][0];  // [wq][c(64)][q(16)] f32 (4096)
  float* ml = ob + 4096;           // [wq][2][16]
  if (kh == 1) {
    if (lg == 0) { ml[wq * 32 + l15] = mreg; ml[wq * 32 + 16 + l15] = lreg; }
#pragma unroll
    for (int cf = 0; cf < 4; ++cf)
#pragma unroll
      for (int i = 0; i < 4; ++i)
        ob[wq * 1024 + (cf * 16 + lg * 4 + i) * 16 + l15] = O[cf][i];
  }
  __syncthreads();
  if (kh == 0) {
    float m1 = ml[wq * 32 + l15], l1 = ml[wq * 32 + 16 + l15];
    float nm = fmaxf(mreg, m1);
    float a0 = __expf(mreg - nm), a1 = __expf(m1 - nm);
    float inv = 1.f / (lreg * a0 + l1 * a1);
#pragma unroll
    for (int cf = 0; cf < 4; ++cf)
#pragma unroll
      for (int i = 0; i < 4; ++i) {
        int idx = wq * 1024 + (cf * 16 + lg * 4 + i) * 16 + l15;
        ob[idx] = (O[cf][i] * a0 + ob[idx] * a1) * inv;
      }
  }
  __syncthreads();
  {  // cooperative gated store: thread -> (q=tid>>3, c=(tid&7)*8 ..+7), coalesced
    int q = tid >> 3, cb = (tid & 7) * 8;
    int wq2 = q >> 4, ql = q & 15;
    size_t row = (size_t)(b * 2048 + qt * 64 + q) * 1024 + h * 64 + cb;
    short8 g8 = *(const short8*)(gws + row);
    short8 o8;
#pragma unroll
    for (int j = 0; j < 8; ++j) {
      float v = ob[wq2 * 1024 + (cb + j) * 16 + ql];
      o8[j] = (short)f2bf(v * bf2f((u16)g8[j]));
    }
    *(short8*)(og + row) = o8;
  }
}

extern "C" void kernel_launch(void* const* d_in, const int* in_sizes, int n_in,
                              void* d_out, int out_size, void* d_ws, size_t ws_size,
                              hipStream_t stream) {
  const float* x    = (const float*)d_in[0];
  const float* mask = (const float*)d_in[1];
  const float* bias = (const float*)d_in[2];
  const float* wq   = (const float*)d_in[3];
  const float* wk   = (const float*)d_in[4];
  const float* wv   = (const float*)d_in[5];
  const float* wg   = (const float*)d_in[6];
  const float* bg   = (const float*)d_in[7];
  const float* wo   = (const float*)d_in[8];
  const float* bo   = (const float*)d_in[9];
  float* out = (float*)d_out;

  char* ws = (char*)d_ws;
  const size_t MB = 1ull << 20;
  u16* xb   = (u16*)(ws + 0);        // 4096x1024 bf16 input          (8 MB)
  u16* wt   = (u16*)(ws + 8 * MB);   // 4x WT [1024][1024] bf16       (8 MB)
  u16* wot  = (u16*)(ws + 16 * MB);  // WOT [1024][1024] bf16         (2 MB)
  u16* proj = (u16*)(ws + 18 * MB);  // q,k,v,g each 4096x1024 bf16   (32 MB)
  u16* vtp  = (u16*)(ws + 50 * MB);  // VT [b,h,c,s] bf16             (8 MB)
  u16* og   = (u16*)(ws + 58 * MB);  // gated attention out bf16      (8 MB)
  const size_t PSZ = (size_t)4096 * 1024;

  convert_bf16_kernel<<<2048, 256, 0, stream>>>(x, xb, 4096 * 1024);

  dim3 tg(16, 16);
  transpose_w64<<<tg, 256, 0, stream>>>(wq, wt + 0 * 1048576, 1024, 1024);
  transpose_w64<<<tg, 256, 0, stream>>>(wk, wt + 1 * 1048576, 1024, 1024);
  transpose_w64<<<tg, 256, 0, stream>>>(wv, wt + 2 * 1048576, 1024, 1024);
  transpose_w64<<<tg, 256, 0, stream>>>(wg, wt + 3 * 1048576, 1024, 1024);
  transpose_w64<<<tg, 256, 0, stream>>>(wo, wot, 1024, 1024);

  gemm_bt128<<<dim3(32, 8, 4), 256, 0, stream>>>(xb, wt, (void*)proj, bg, -1);

  transpose_v64<<<dim3(32, 32), 256, 0, stream>>>(proj + 2 * PSZ, vtp);

  attn_kernel<<<dim3(64, 16), 512, 0, stream>>>(proj, proj + PSZ, vtp, proj + 3 * PSZ,
                                                bias, mask, og);

  gemm_bt128<<<dim3(32, 8, 1), 256, 0, stream>>>(og, wot, (void*)out, bo, 4);
}